// Round 2
// baseline (3246.591 us; speedup 1.0000x reference)
//
#include <hip/hip_runtime.h>
#include <hip/hip_bf16.h>

// Sizes (fixed by the problem)
#define BATCH 4
#define NPTS  8192
#define NSAMP 2048
#define NK    16
#define CFEAT 64
#define CG    67      // 3 + 64
#define CO1   128
#define CCAT  192     // 64 + 128
#define CO2   128

#define DEV __device__ __forceinline__

// --- exact-rounding helpers (block fp-contraction; match reference numerics) ---
DEV float n3(float x, float y, float z) {
    // matches sum(a*a, -1): elementwise square, then sequential reduce
    return __fadd_rn(__fadd_rn(__fmul_rn(x, x), __fmul_rn(y, y)), __fmul_rn(z, z));
}
DEV float dot3(float ax, float ay, float az, float bx, float by, float bz) {
    // matches einsum('bmc,bnc->bmn') lowered to K=3 GEMM: in-order FMA chain
    return __fmaf_rn(az, bz, __fmaf_rn(ay, by, __fmul_rn(ax, bx)));
}
DEV float sqd_expand(float an, float bn, float d) {
    // (an + bn) - 2*d  — matches  sum(a*a) + sum(b*b) - 2*einsum
    return __fsub_rn(__fadd_rn(an, bn), __fmul_rn(2.0f, d));
}

// ============================================================================
// K0: transpose features (B,64,8192) -> featT (B,8192,64) for coalesced gathers
// ============================================================================
__global__ __launch_bounds__(256) void transpose_kernel(const float* __restrict__ F,
                                                        float* __restrict__ T) {
    __shared__ float tile[64][65];
    const int b = blockIdx.y;
    const int n0 = blockIdx.x * 64;
    const int tx = threadIdx.x & 63, ty = threadIdx.x >> 6; // ty: 0..3
    const float* Fb = F + (size_t)b * CFEAT * NPTS;
    float* Tb = T + (size_t)b * NPTS * CFEAT;
#pragma unroll
    for (int i = 0; i < 16; i++) {
        int c = ty + i * 4;
        tile[c][tx] = Fb[(size_t)c * NPTS + n0 + tx];
    }
    __syncthreads();
#pragma unroll
    for (int i = 0; i < 16; i++) {
        int r = ty + i * 4;
        Tb[(size_t)(n0 + r) * CFEAT + tx] = tile[tx][r];
    }
}

// ============================================================================
// K1: farthest point sampling. One block per batch. 256 threads, 32 pts/thread
// in registers; xyz mirrored in LDS for centroid broadcast.
// Writes new_xyz (B,2048,3).
// ============================================================================
__global__ __launch_bounds__(256) void fps_kernel(const float* __restrict__ xyz,
                                                  float* __restrict__ new_xyz) {
    const int b = blockIdx.x;
    const int t = threadIdx.x;
    const int lane = t & 63, wv = t >> 6;
    const float* X = xyz + (size_t)b * NPTS * 3;

    __shared__ float sx[NPTS], sy[NPTS], sz[NPTS];   // 96 KiB
    __shared__ float rbv[4];
    __shared__ int   rbi[4];

    float px[32], py[32], pz[32], dist[32];
#pragma unroll
    for (int j = 0; j < 32; j++) {
        int p = t + j * 256;
        float x = X[p * 3 + 0], y = X[p * 3 + 1], z = X[p * 3 + 2];
        px[j] = x; py[j] = y; pz[j] = z;
        sx[p] = x; sy[p] = y; sz[p] = z;
        dist[j] = 1e10f;
    }
    __syncthreads();

    float cx = sx[0], cy = sy[0], cz = sz[0];   // first sampled index is 0
    if (t == 0) {
        size_t o = (size_t)b * NSAMP * 3;
        new_xyz[o + 0] = cx; new_xyz[o + 1] = cy; new_xyz[o + 2] = cz;
    }

    for (int s = 1; s < NSAMP; s++) {
        float bv = -1.0f;
        int bi = 0x7fffffff;
#pragma unroll
        for (int j = 0; j < 32; j++) {
            // d = ((dx*dx + dy*dy) + dz*dz), no fma (must match numpy exactly)
            float dx = __fsub_rn(px[j], cx);
            float dy = __fsub_rn(py[j], cy);
            float dz = __fsub_rn(pz[j], cz);
            float d = __fadd_rn(__fadd_rn(__fmul_rn(dx, dx), __fmul_rn(dy, dy)),
                                __fmul_rn(dz, dz));
            float nd = fminf(dist[j], d);
            dist[j] = nd;
            bool better = (nd > bv);     // strict > keeps lowest index (j asc => p asc)
            bv = better ? nd : bv;
            bi = better ? (t + j * 256) : bi;
        }
        // wave butterfly argmax, tie -> lower index
#pragma unroll
        for (int off = 32; off > 0; off >>= 1) {
            float ov = __shfl_xor(bv, off);
            int   oi = __shfl_xor(bi, off);
            bool take = (ov > bv) || (ov == bv && oi < bi);
            bv = take ? ov : bv;
            bi = take ? oi : bi;
        }
        if (lane == 0) { rbv[wv] = bv; rbi[wv] = bi; }
        __syncthreads();
        float v0 = rbv[0]; int i0 = rbi[0];
#pragma unroll
        for (int w = 1; w < 4; w++) {
            float v = rbv[w]; int i = rbi[w];
            bool take = (v > v0) || (v == v0 && i < i0);
            v0 = take ? v : v0;
            i0 = take ? i : i0;
        }
        cx = sx[i0]; cy = sy[i0]; cz = sz[i0];   // LDS broadcast
        if (t == 0) {
            size_t o = ((size_t)b * NSAMP + s) * 3;
            new_xyz[o + 0] = cx; new_xyz[o + 1] = cy; new_xyz[o + 2] = cz;
        }
        __syncthreads();   // protects rbv/rbi WAR for next iteration
    }
}

// ============================================================================
// K2: ball query. One wave per query; scan points in rounds of 64 in index
// order, collect first 16 within radius^2=0.04, pad with first. Early exit.
// ============================================================================
__global__ __launch_bounds__(256) void ballq_kernel(const float* __restrict__ xyz,
                                                    const float* __restrict__ new_xyz,
                                                    int* __restrict__ nidx) {
    const int wv = threadIdx.x >> 6, lane = threadIdx.x & 63;
    const int q = blockIdx.x * 4 + wv;          // 0..8191
    const int b = q >> 11;
    const float* X = xyz + (size_t)b * NPTS * 3;
    const float* Q = new_xyz + (size_t)q * 3;
    const float qx = Q[0], qy = Q[1], qz = Q[2];
    const float an = n3(qx, qy, qz);

    __shared__ int nb[4][NK];
    int cnt = 0;
    for (int base = 0; base < NPTS && cnt < NK; base += 64) {
        int p = base + lane;
        float x = X[p * 3 + 0], y = X[p * 3 + 1], z = X[p * 3 + 2];
        float bn = n3(x, y, z);
        float dt = dot3(qx, qy, qz, x, y, z);
        float sq = sqd_expand(an, bn, dt);
        bool in = (sq <= 0.04f);                // == (NOT sq > r^2)
        unsigned long long m = __ballot(in);
        if (in) {
            int pos = cnt + (int)__popcll(m & ((1ull << lane) - 1ull));
            if (pos < NK) nb[wv][pos] = p;
        }
        cnt += (int)__popcll(m);
    }
    __syncthreads();
    if (lane < NK) {
        int c = cnt < NK ? cnt : NK;
        int v = (lane < c) ? nb[wv][lane] : nb[wv][0];  // pad with first
        nidx[(size_t)q * NK + lane] = v;
    }
}

// ============================================================================
// K3: grouping + W1 (128x67) + relu + max over k -> subxT (B,2048,128)
// One wave per sample; lane c gathers feature channel c; per-k matvec with
// W1^T in LDS, grouped values broadcast via shfl.
// ============================================================================
__global__ __launch_bounds__(256) void group_mlp_kernel(const float* __restrict__ xyz,
                                                        const float* __restrict__ featT,
                                                        const float* __restrict__ new_xyz,
                                                        const int* __restrict__ nidx,
                                                        const float* __restrict__ W1,
                                                        float* __restrict__ subxT) {
    __shared__ float w1t[CG * CO1];   // [d][o], 33.5 KiB
    for (int i = threadIdx.x; i < CG * CO1; i += 256) {
        int d = i >> 7, o = i & 127;
        w1t[i] = W1[(size_t)o * CG + d];
    }
    __syncthreads();
    const int lane = threadIdx.x & 63, wv = threadIdx.x >> 6;

    for (int q = blockIdx.x * 4 + wv; q < BATCH * NSAMP; q += gridDim.x * 4) {
        const int b = q >> 11;
        const float* Q = new_xyz + (size_t)q * 3;
        const float qx = Q[0], qy = Q[1], qz = Q[2];
        const int* NB = nidx + (size_t)q * NK;
        float m0 = 0.0f, m1 = 0.0f;  // max(relu(h)) == max(0, max h)
#pragma unroll 1
        for (int k = 0; k < NK; k++) {
            const int n = NB[k];
            const float* P = xyz + ((size_t)b * NPTS + n) * 3;
            float rx = P[0] - qx, ry = P[1] - qy, rz = P[2] - qz;
            float fv = featT[((size_t)b * NPTS + n) * CFEAT + lane];
            float a0 = fmaf(w1t[0 * CO1 + lane], rx,
                       fmaf(w1t[1 * CO1 + lane], ry, w1t[2 * CO1 + lane] * rz));
            float a1 = fmaf(w1t[0 * CO1 + 64 + lane], rx,
                       fmaf(w1t[1 * CO1 + 64 + lane], ry, w1t[2 * CO1 + 64 + lane] * rz));
#pragma unroll
            for (int d = 3; d < CG; d++) {
                float g = __shfl(fv, d - 3);
                a0 = fmaf(w1t[d * CO1 + lane], g, a0);
                a1 = fmaf(w1t[d * CO1 + 64 + lane], g, a1);
            }
            m0 = fmaxf(m0, a0);
            m1 = fmaxf(m1, a1);
        }
        subxT[(size_t)q * CO1 + lane] = m0;
        subxT[(size_t)q * CO1 + 64 + lane] = m1;
    }
}

// ============================================================================
// K4: 3-NN interpolation + concat + W2 (128x192) + relu -> out (B,128,8192)
// One wave per output point. Top-3 via per-lane sorted insert + butterfly merge
// with (d, idx) lexicographic compare (== lax.top_k stability).
// ============================================================================
DEV void ins3(float dd, int jj,
              float& d0, int& i0, float& d1, int& i1, float& d2, int& i2) {
    bool c2 = (dd < d2) || (dd == d2 && jj < i2);
    if (c2) { d2 = dd; i2 = jj; }
    bool c1 = (d2 < d1) || (d2 == d1 && i2 < i1);
    if (c1) { float tv = d1; int ti = i1; d1 = d2; i1 = i2; d2 = tv; i2 = ti; }
    bool c0 = (d1 < d0) || (d1 == d0 && i1 < i0);
    if (c0) { float tv = d0; int ti = i0; d0 = d1; i0 = i1; d1 = tv; i1 = ti; }
}

__global__ __launch_bounds__(256) void interp_w2_kernel(const float* __restrict__ xyz,
                                                        const float* __restrict__ new_xyz,
                                                        const float* __restrict__ featT,
                                                        const float* __restrict__ subxT,
                                                        const float* __restrict__ W2,
                                                        float* __restrict__ out) {
    __shared__ float w2t[CCAT * CO2];  // [d][o], 96 KiB
    __shared__ float catb[4][CCAT];
    for (int i = threadIdx.x; i < CCAT * CO2; i += 256) {
        int d = i >> 7, o = i & 127;
        w2t[i] = W2[(size_t)o * CCAT + d];
    }
    __syncthreads();
    const int lane = threadIdx.x & 63, wv = threadIdx.x >> 6;

    for (int q = blockIdx.x * 4 + wv; q < BATCH * NPTS; q += gridDim.x * 4) {
        const int b = q >> 13, n = q & (NPTS - 1);
        const float* P = xyz + (size_t)q * 3;
        const float qx = P[0], qy = P[1], qz = P[2];
        const float an = n3(qx, qy, qz);

        float d0 = 1e30f, d1 = 1e30f, d2 = 1e30f;
        int i0 = 0x7fffffff, i1 = 0x7fffffff, i2 = 0x7fffffff;
        for (int j = lane; j < NSAMP; j += 64) {
            const float* C = new_xyz + ((size_t)b * NSAMP + j) * 3;
            float x = C[0], y = C[1], z = C[2];
            float bn = n3(x, y, z);
            float dt = dot3(qx, qy, qz, x, y, z);
            float dd = sqd_expand(an, bn, dt);
            ins3(dd, j, d0, i0, d1, i1, d2, i2);
        }
#pragma unroll
        for (int off = 32; off > 0; off >>= 1) {
            float e0 = __shfl_xor(d0, off); int f0 = __shfl_xor(i0, off);
            float e1 = __shfl_xor(d1, off); int f1 = __shfl_xor(i1, off);
            float e2 = __shfl_xor(d2, off); int f2 = __shfl_xor(i2, off);
            ins3(e0, f0, d0, i0, d1, i1, d2, i2);
            ins3(e1, f1, d0, i0, d1, i1, d2, i2);
            ins3(e2, f2, d0, i0, d1, i1, d2, i2);
        }
        float w0 = 1.0f / (d0 + 1e-8f);
        float w1 = 1.0f / (d1 + 1e-8f);
        float w2 = 1.0f / (d2 + 1e-8f);
        float sw = (w0 + w1) + w2;
        w0 /= sw; w1 /= sw; w2 /= sw;

        // lerp channels c=lane and c=lane+64 (coalesced row gathers)
        const float* S = subxT + (size_t)b * NSAMP * CO1;
        float L0 = S[(size_t)i0 * CO1 + lane] * w0
                 + S[(size_t)i1 * CO1 + lane] * w1
                 + S[(size_t)i2 * CO1 + lane] * w2;
        float L1 = S[(size_t)i0 * CO1 + 64 + lane] * w0
                 + S[(size_t)i1 * CO1 + 64 + lane] * w1
                 + S[(size_t)i2 * CO1 + 64 + lane] * w2;

        float fv = featT[((size_t)b * NPTS + n) * CFEAT + lane];
        catb[wv][lane] = fv;          // cat[0:64]   = features
        catb[wv][64 + lane] = L0;     // cat[64:128] = lerp lo
        catb[wv][128 + lane] = L1;    // cat[128:192]= lerp hi
        __builtin_amdgcn_s_waitcnt(0);  // drain ds_writes (in-order DS pipe, same wave)

        float a0 = 0.0f, a1 = 0.0f;
#pragma unroll 8
        for (int d = 0; d < CCAT; d++) {
            float cv = catb[wv][d];
            a0 = fmaf(w2t[d * CO2 + lane], cv, a0);
            a1 = fmaf(w2t[d * CO2 + 64 + lane], cv, a1);
        }
        out[((size_t)b * CO2 + lane) * NPTS + n] = fmaxf(a0, 0.0f);
        out[((size_t)b * CO2 + 64 + lane) * NPTS + n] = fmaxf(a1, 0.0f);
    }
}

// ============================================================================
extern "C" void kernel_launch(void* const* d_in, const int* in_sizes, int n_in,
                              void* d_out, int out_size, void* d_ws, size_t ws_size,
                              hipStream_t stream) {
    const float* xyz      = (const float*)d_in[0];  // (4,8192,3)
    const float* features = (const float*)d_in[1];  // (4,64,8192)
    const float* W1       = (const float*)d_in[2];  // (128,67)
    const float* W2       = (const float*)d_in[3];  // (128,192)
    float* out = (float*)d_out;                     // (4,128,8192)

    // workspace layout (floats/ints), total ~12.6 MB
    float* featT   = (float*)d_ws;                          // 4*8192*64
    float* new_xyz = featT + (size_t)BATCH * NPTS * CFEAT;  // 4*2048*3
    int*   nidx    = (int*)(new_xyz + (size_t)BATCH * NSAMP * 3); // 4*2048*16
    float* subxT   = (float*)(nidx + (size_t)BATCH * NSAMP * NK); // 4*2048*128

    transpose_kernel<<<dim3(NPTS / 64, BATCH), 256, 0, stream>>>(features, featT);
    fps_kernel<<<BATCH, 256, 0, stream>>>(xyz, new_xyz);
    ballq_kernel<<<(BATCH * NSAMP) / 4, 256, 0, stream>>>(xyz, new_xyz, nidx);
    group_mlp_kernel<<<512, 256, 0, stream>>>(xyz, featT, new_xyz, nidx, W1, subxT);
    interp_w2_kernel<<<256, 256, 0, stream>>>(xyz, new_xyz, featT, subxT, W2, out);
}

// Round 3
// 3067.441 us; speedup vs baseline: 1.0584x; 1.0584x over previous
//
#include <hip/hip_runtime.h>
#include <hip/hip_bf16.h>

// Sizes (fixed by the problem)
#define BATCH 4
#define NPTS  8192
#define NSAMP 2048
#define NK    16
#define CFEAT 64
#define CG    67      // 3 + 64
#define CO1   128
#define CCAT  192     // 64 + 128
#define CO2   128

#define DEV __device__ __forceinline__

// --- exact-rounding helpers (block fp-contraction; match reference numerics) ---
DEV float n3(float x, float y, float z) {
    // matches sum(a*a, -1): elementwise square, then sequential reduce
    return __fadd_rn(__fadd_rn(__fmul_rn(x, x), __fmul_rn(y, y)), __fmul_rn(z, z));
}
DEV float dot3(float ax, float ay, float az, float bx, float by, float bz) {
    // matches einsum('bmc,bnc->bmn') lowered to K=3 GEMM: in-order FMA chain
    return __fmaf_rn(az, bz, __fmaf_rn(ay, by, __fmul_rn(ax, bx)));
}
DEV float sqd_expand(float an, float bn, float d) {
    // (an + bn) - 2*d  — matches  sum(a*a) + sum(b*b) - 2*einsum
    return __fsub_rn(__fadd_rn(an, bn), __fmul_rn(2.0f, d));
}

// ============================================================================
// K0: transpose features (B,64,8192) -> featT (B,8192,64) for coalesced gathers
// ============================================================================
__global__ __launch_bounds__(256) void transpose_kernel(const float* __restrict__ F,
                                                        float* __restrict__ T) {
    __shared__ float tile[64][65];
    const int b = blockIdx.y;
    const int n0 = blockIdx.x * 64;
    const int tx = threadIdx.x & 63, ty = threadIdx.x >> 6; // ty: 0..3
    const float* Fb = F + (size_t)b * CFEAT * NPTS;
    float* Tb = T + (size_t)b * NPTS * CFEAT;
#pragma unroll
    for (int i = 0; i < 16; i++) {
        int c = ty + i * 4;
        tile[c][tx] = Fb[(size_t)c * NPTS + n0 + tx];
    }
    __syncthreads();
#pragma unroll
    for (int i = 0; i < 16; i++) {
        int r = ty + i * 4;
        Tb[(size_t)(n0 + r) * CFEAT + tx] = tile[tx][r];
    }
}

// ============================================================================
// K1: farthest point sampling. One block (1024 threads) per batch.
// Thread t owns contiguous points [8t, 8t+8) in registers. Argmax packed as
// u64 (value_bits<<32)|~idx  (dist>=0 so f32 bits are order-monotone; max of
// pk == max value with min-index tie-break == jnp.argmax first-occurrence).
// Flat LDS reduce: all 1024 write, wave 0 reduces, broadcasts centroid.
// ============================================================================
__global__ __launch_bounds__(1024) void fps_kernel(const float* __restrict__ xyz,
                                                   float* __restrict__ new_xyz) {
    const int b = blockIdx.x;
    const int t = threadIdx.x;              // 0..1023
    const float* X = xyz + (size_t)b * NPTS * 3;

    __shared__ float sx[NPTS], sy[NPTS], sz[NPTS];      // 96 KiB
    __shared__ unsigned long long red[1024];            // 8 KiB
    __shared__ float bc[4];

    float px[8], py[8], pz[8], dist[8];
    // load 8 points = 24 floats = 6 float4 (96B per thread, 16B aligned)
    {
        const float4* X4 = (const float4*)X;
        float4 f0 = X4[t * 6 + 0], f1 = X4[t * 6 + 1], f2 = X4[t * 6 + 2];
        float4 f3 = X4[t * 6 + 3], f4 = X4[t * 6 + 4], f5 = X4[t * 6 + 5];
        px[0] = f0.x; py[0] = f0.y; pz[0] = f0.z;
        px[1] = f0.w; py[1] = f1.x; pz[1] = f1.y;
        px[2] = f1.z; py[2] = f1.w; pz[2] = f2.x;
        px[3] = f2.y; py[3] = f2.z; pz[3] = f2.w;
        px[4] = f3.x; py[4] = f3.y; pz[4] = f3.z;
        px[5] = f3.w; py[5] = f4.x; pz[5] = f4.y;
        px[6] = f4.z; py[6] = f4.w; pz[6] = f5.x;
        px[7] = f5.y; py[7] = f5.z; pz[7] = f5.w;
#pragma unroll
        for (int j = 0; j < 8; j++) {
            int p = t * 8 + j;
            sx[p] = px[j]; sy[p] = py[j]; sz[p] = pz[j];
            dist[j] = 1e10f;
        }
    }
    __syncthreads();

    float cx = sx[0], cy = sy[0], cz = sz[0];   // first sampled index is 0
    if (t == 0) {
        size_t o = (size_t)b * NSAMP * 3;
        new_xyz[o + 0] = cx; new_xyz[o + 1] = cy; new_xyz[o + 2] = cz;
    }

    for (int s = 1; s < NSAMP; s++) {
        float bv = -1.0f;
        int bj = 0;
#pragma unroll
        for (int j = 0; j < 8; j++) {
            // d = ((dx*dx + dy*dy) + dz*dz), no fma (must match numpy exactly)
            float dx = __fsub_rn(px[j], cx);
            float dy = __fsub_rn(py[j], cy);
            float dz = __fsub_rn(pz[j], cz);
            float d = __fadd_rn(__fadd_rn(__fmul_rn(dx, dx), __fmul_rn(dy, dy)),
                                __fmul_rn(dz, dz));
            float nd = fminf(dist[j], d);
            dist[j] = nd;
            bool better = (nd > bv);   // strict > keeps lowest j
            bv = better ? nd : bv;
            bj = better ? j : bj;
        }
        int bidx = t * 8 + bj;
        red[t] = ((unsigned long long)__float_as_uint(bv) << 32)
               | (unsigned int)(~bidx);
        __syncthreads();                       // bar1: red[] complete

        if (t < 64) {                          // wave 0 reduces 1024 -> 1
            unsigned long long v[16];
#pragma unroll
            for (int k = 0; k < 16; k++) v[k] = red[t + (k << 6)];
#pragma unroll
            for (int st = 8; st > 0; st >>= 1)
#pragma unroll
                for (int k = 0; k < st; k++)
                    if (v[k + st] > v[k]) v[k] = v[k + st];
            unsigned long long m = v[0];
#pragma unroll
            for (int off = 32; off > 0; off >>= 1) {
                unsigned long long o = __shfl_xor(m, off);
                if (o > m) m = o;
            }
            if (t == 0) {
                int idx = (int)(~(unsigned int)(m & 0xFFFFFFFFull));
                float x = sx[idx], y = sy[idx], z = sz[idx];
                bc[0] = x; bc[1] = y; bc[2] = z;
                size_t o = ((size_t)b * NSAMP + s) * 3;
                new_xyz[o + 0] = x; new_xyz[o + 1] = y; new_xyz[o + 2] = z;
            }
        }
        __syncthreads();                       // bar2: bc ready
        cx = bc[0]; cy = bc[1]; cz = bc[2];
    }
}

// ============================================================================
// K2: ball query. One wave per query; scan points in rounds of 64 in index
// order, collect first 16 within radius^2=0.04, pad with first. Early exit.
// ============================================================================
__global__ __launch_bounds__(256) void ballq_kernel(const float* __restrict__ xyz,
                                                    const float* __restrict__ new_xyz,
                                                    int* __restrict__ nidx) {
    const int wv = threadIdx.x >> 6, lane = threadIdx.x & 63;
    const int q = blockIdx.x * 4 + wv;          // 0..8191
    const int b = q >> 11;
    const float* X = xyz + (size_t)b * NPTS * 3;
    const float* Q = new_xyz + (size_t)q * 3;
    const float qx = Q[0], qy = Q[1], qz = Q[2];
    const float an = n3(qx, qy, qz);

    __shared__ int nb[4][NK];
    int cnt = 0;
    for (int base = 0; base < NPTS && cnt < NK; base += 64) {
        int p = base + lane;
        float x = X[p * 3 + 0], y = X[p * 3 + 1], z = X[p * 3 + 2];
        float bn = n3(x, y, z);
        float dt = dot3(qx, qy, qz, x, y, z);
        float sq = sqd_expand(an, bn, dt);
        bool in = (sq <= 0.04f);                // == (NOT sq > r^2)
        unsigned long long m = __ballot(in);
        if (in) {
            int pos = cnt + (int)__popcll(m & ((1ull << lane) - 1ull));
            if (pos < NK) nb[wv][pos] = p;
        }
        cnt += (int)__popcll(m);
    }
    __syncthreads();
    if (lane < NK) {
        int c = cnt < NK ? cnt : NK;
        int v = (lane < c) ? nb[wv][lane] : nb[wv][0];  // pad with first
        nidx[(size_t)q * NK + lane] = v;
    }
}

// ============================================================================
// K3: grouping + W1 (128x67) + relu + max over k -> subxT (B,2048,128)
// One wave per sample; lane c gathers feature channel c; per-k matvec with
// W1^T in LDS, grouped values broadcast via shfl.
// ============================================================================
__global__ __launch_bounds__(256) void group_mlp_kernel(const float* __restrict__ xyz,
                                                        const float* __restrict__ featT,
                                                        const float* __restrict__ new_xyz,
                                                        const int* __restrict__ nidx,
                                                        const float* __restrict__ W1,
                                                        float* __restrict__ subxT) {
    __shared__ float w1t[CG * CO1];   // [d][o], 33.5 KiB
    for (int i = threadIdx.x; i < CG * CO1; i += 256) {
        int d = i >> 7, o = i & 127;
        w1t[i] = W1[(size_t)o * CG + d];
    }
    __syncthreads();
    const int lane = threadIdx.x & 63, wv = threadIdx.x >> 6;

    for (int q = blockIdx.x * 4 + wv; q < BATCH * NSAMP; q += gridDim.x * 4) {
        const int b = q >> 11;
        const float* Q = new_xyz + (size_t)q * 3;
        const float qx = Q[0], qy = Q[1], qz = Q[2];
        const int* NB = nidx + (size_t)q * NK;
        float m0 = 0.0f, m1 = 0.0f;  // max(relu(h)) == max(0, max h)
#pragma unroll 1
        for (int k = 0; k < NK; k++) {
            const int n = NB[k];
            const float* P = xyz + ((size_t)b * NPTS + n) * 3;
            float rx = P[0] - qx, ry = P[1] - qy, rz = P[2] - qz;
            float fv = featT[((size_t)b * NPTS + n) * CFEAT + lane];
            float a0 = fmaf(w1t[0 * CO1 + lane], rx,
                       fmaf(w1t[1 * CO1 + lane], ry, w1t[2 * CO1 + lane] * rz));
            float a1 = fmaf(w1t[0 * CO1 + 64 + lane], rx,
                       fmaf(w1t[1 * CO1 + 64 + lane], ry, w1t[2 * CO1 + 64 + lane] * rz));
#pragma unroll
            for (int d = 3; d < CG; d++) {
                float g = __shfl(fv, d - 3);
                a0 = fmaf(w1t[d * CO1 + lane], g, a0);
                a1 = fmaf(w1t[d * CO1 + 64 + lane], g, a1);
            }
            m0 = fmaxf(m0, a0);
            m1 = fmaxf(m1, a1);
        }
        subxT[(size_t)q * CO1 + lane] = m0;
        subxT[(size_t)q * CO1 + 64 + lane] = m1;
    }
}

// ============================================================================
// K4: 3-NN interpolation + concat + W2 (128x192) + relu -> out (B,128,8192)
// One wave per output point. Top-3 via per-lane sorted insert + butterfly merge
// with (d, idx) lexicographic compare (== lax.top_k stability).
// ============================================================================
DEV void ins3(float dd, int jj,
              float& d0, int& i0, float& d1, int& i1, float& d2, int& i2) {
    bool c2 = (dd < d2) || (dd == d2 && jj < i2);
    if (c2) { d2 = dd; i2 = jj; }
    bool c1 = (d2 < d1) || (d2 == d1 && i2 < i1);
    if (c1) { float tv = d1; int ti = i1; d1 = d2; i1 = i2; d2 = tv; i2 = ti; }
    bool c0 = (d1 < d0) || (d1 == d0 && i1 < i0);
    if (c0) { float tv = d0; int ti = i0; d0 = d1; i0 = i1; d1 = tv; i1 = ti; }
}

__global__ __launch_bounds__(256) void interp_w2_kernel(const float* __restrict__ xyz,
                                                        const float* __restrict__ new_xyz,
                                                        const float* __restrict__ featT,
                                                        const float* __restrict__ subxT,
                                                        const float* __restrict__ W2,
                                                        float* __restrict__ out) {
    __shared__ float w2t[CCAT * CO2];  // [d][o], 96 KiB
    __shared__ float catb[4][CCAT];
    for (int i = threadIdx.x; i < CCAT * CO2; i += 256) {
        int d = i >> 7, o = i & 127;
        w2t[i] = W2[(size_t)o * CCAT + d];
    }
    __syncthreads();
    const int lane = threadIdx.x & 63, wv = threadIdx.x >> 6;

    for (int q = blockIdx.x * 4 + wv; q < BATCH * NPTS; q += gridDim.x * 4) {
        const int b = q >> 13, n = q & (NPTS - 1);
        const float* P = xyz + (size_t)q * 3;
        const float qx = P[0], qy = P[1], qz = P[2];
        const float an = n3(qx, qy, qz);

        float d0 = 1e30f, d1 = 1e30f, d2 = 1e30f;
        int i0 = 0x7fffffff, i1 = 0x7fffffff, i2 = 0x7fffffff;
        for (int j = lane; j < NSAMP; j += 64) {
            const float* C = new_xyz + ((size_t)b * NSAMP + j) * 3;
            float x = C[0], y = C[1], z = C[2];
            float bn = n3(x, y, z);
            float dt = dot3(qx, qy, qz, x, y, z);
            float dd = sqd_expand(an, bn, dt);
            ins3(dd, j, d0, i0, d1, i1, d2, i2);
        }
#pragma unroll
        for (int off = 32; off > 0; off >>= 1) {
            float e0 = __shfl_xor(d0, off); int f0 = __shfl_xor(i0, off);
            float e1 = __shfl_xor(d1, off); int f1 = __shfl_xor(i1, off);
            float e2 = __shfl_xor(d2, off); int f2 = __shfl_xor(i2, off);
            ins3(e0, f0, d0, i0, d1, i1, d2, i2);
            ins3(e1, f1, d0, i0, d1, i1, d2, i2);
            ins3(e2, f2, d0, i0, d1, i1, d2, i2);
        }
        float w0 = 1.0f / (d0 + 1e-8f);
        float w1 = 1.0f / (d1 + 1e-8f);
        float w2 = 1.0f / (d2 + 1e-8f);
        float sw = (w0 + w1) + w2;
        w0 /= sw; w1 /= sw; w2 /= sw;

        // lerp channels c=lane and c=lane+64 (coalesced row gathers)
        const float* S = subxT + (size_t)b * NSAMP * CO1;
        float L0 = S[(size_t)i0 * CO1 + lane] * w0
                 + S[(size_t)i1 * CO1 + lane] * w1
                 + S[(size_t)i2 * CO1 + lane] * w2;
        float L1 = S[(size_t)i0 * CO1 + 64 + lane] * w0
                 + S[(size_t)i1 * CO1 + 64 + lane] * w1
                 + S[(size_t)i2 * CO1 + 64 + lane] * w2;

        float fv = featT[((size_t)b * NPTS + n) * CFEAT + lane];
        catb[wv][lane] = fv;          // cat[0:64]   = features
        catb[wv][64 + lane] = L0;     // cat[64:128] = lerp lo
        catb[wv][128 + lane] = L1;    // cat[128:192]= lerp hi
        __builtin_amdgcn_s_waitcnt(0);  // drain ds_writes (in-order DS pipe, same wave)

        float a0 = 0.0f, a1 = 0.0f;
#pragma unroll 8
        for (int d = 0; d < CCAT; d++) {
            float cv = catb[wv][d];
            a0 = fmaf(w2t[d * CO2 + lane], cv, a0);
            a1 = fmaf(w2t[d * CO2 + 64 + lane], cv, a1);
        }
        out[((size_t)b * CO2 + lane) * NPTS + n] = fmaxf(a0, 0.0f);
        out[((size_t)b * CO2 + 64 + lane) * NPTS + n] = fmaxf(a1, 0.0f);
    }
}

// ============================================================================
extern "C" void kernel_launch(void* const* d_in, const int* in_sizes, int n_in,
                              void* d_out, int out_size, void* d_ws, size_t ws_size,
                              hipStream_t stream) {
    const float* xyz      = (const float*)d_in[0];  // (4,8192,3)
    const float* features = (const float*)d_in[1];  // (4,64,8192)
    const float* W1       = (const float*)d_in[2];  // (128,67)
    const float* W2       = (const float*)d_in[3];  // (128,192)
    float* out = (float*)d_out;                     // (4,128,8192)

    // workspace layout (floats/ints), total ~12.6 MB
    float* featT   = (float*)d_ws;                          // 4*8192*64
    float* new_xyz = featT + (size_t)BATCH * NPTS * CFEAT;  // 4*2048*3
    int*   nidx    = (int*)(new_xyz + (size_t)BATCH * NSAMP * 3); // 4*2048*16
    float* subxT   = (float*)(nidx + (size_t)BATCH * NSAMP * NK); // 4*2048*128

    transpose_kernel<<<dim3(NPTS / 64, BATCH), 256, 0, stream>>>(features, featT);
    fps_kernel<<<BATCH, 1024, 0, stream>>>(xyz, new_xyz);
    ballq_kernel<<<(BATCH * NSAMP) / 4, 256, 0, stream>>>(xyz, new_xyz, nidx);
    group_mlp_kernel<<<512, 256, 0, stream>>>(xyz, featT, new_xyz, nidx, W1, subxT);
    interp_w2_kernel<<<256, 256, 0, stream>>>(xyz, new_xyz, featT, subxT, W2, out);
}

// Round 4
// 2833.962 us; speedup vs baseline: 1.1456x; 1.0824x over previous
//
#include <hip/hip_runtime.h>
#include <hip/hip_bf16.h>

// Sizes (fixed by the problem)
#define BATCH 4
#define NPTS  8192
#define NSAMP 2048
#define NK    16
#define CFEAT 64
#define CG    67      // 3 + 64
#define CO1   128
#define CCAT  192     // 64 + 128
#define CO2   128

#define DEV __device__ __forceinline__

// --- exact-rounding helpers (block fp-contraction; match reference numerics) ---
DEV float n3(float x, float y, float z) {
    // matches sum(a*a, -1): elementwise square, then sequential reduce
    return __fadd_rn(__fadd_rn(__fmul_rn(x, x), __fmul_rn(y, y)), __fmul_rn(z, z));
}
DEV float dot3(float ax, float ay, float az, float bx, float by, float bz) {
    // matches einsum('bmc,bnc->bmn') lowered to K=3 GEMM: in-order FMA chain
    return __fmaf_rn(az, bz, __fmaf_rn(ay, by, __fmul_rn(ax, bx)));
}
DEV float sqd_expand(float an, float bn, float d) {
    // (an + bn) - 2*d  — matches  sum(a*a) + sum(b*b) - 2*einsum
    return __fsub_rn(__fadd_rn(an, bn), __fmul_rn(2.0f, d));
}

// ============================================================================
// K0: transpose features (B,64,8192) -> featT (B,8192,64) for coalesced gathers
// ============================================================================
__global__ __launch_bounds__(256) void transpose_kernel(const float* __restrict__ F,
                                                        float* __restrict__ T) {
    __shared__ float tile[64][65];
    const int b = blockIdx.y;
    const int n0 = blockIdx.x * 64;
    const int tx = threadIdx.x & 63, ty = threadIdx.x >> 6; // ty: 0..3
    const float* Fb = F + (size_t)b * CFEAT * NPTS;
    float* Tb = T + (size_t)b * NPTS * CFEAT;
#pragma unroll
    for (int i = 0; i < 16; i++) {
        int c = ty + i * 4;
        tile[c][tx] = Fb[(size_t)c * NPTS + n0 + tx];
    }
    __syncthreads();
#pragma unroll
    for (int i = 0; i < 16; i++) {
        int r = ty + i * 4;
        Tb[(size_t)(n0 + r) * CFEAT + tx] = tile[tx][r];
    }
}

// ============================================================================
// K1: farthest point sampling. One block (512 threads = 8 waves) per batch.
// Thread t owns contiguous points [16t, 16t+16) in registers.
// Per iteration, ONE barrier:
//   update -> per-thread argmax (fmax tree + descending == scan)
//   -> wave f32 butterfly max -> ballot/lowest-lane for index
//   -> lane0 writes packed u64 winner to wred[parity][wave]
//   -> barrier -> ALL threads redundantly reduce the 8 winners (LDS broadcast
//      reads) and fetch the centroid themselves. Parity double-buffer removes
//      the WAR barrier (a wave can be at most 1 iter ahead -> other buffer).
// Packing: (f32_bits(v)<<32)|~idx : v>=0 so bits are order-monotone; u64 max
// = max value with min-index tie-break == jnp.argmax first-occurrence.
// ============================================================================
__global__ __launch_bounds__(512) void fps_kernel(const float* __restrict__ xyz,
                                                  float* __restrict__ new_xyz) {
    const int b = blockIdx.x;
    const int t = threadIdx.x;              // 0..511
    const int lane = t & 63, wv = t >> 6;   // 8 waves
    const float* X = xyz + (size_t)b * NPTS * 3;

    __shared__ float sx[NPTS], sy[NPTS], sz[NPTS];      // 96 KiB
    __shared__ unsigned long long wred[2][8];

    float px[16], py[16], pz[16], dist[16];
    // load 16 points = 48 floats = 12 float4 per thread
    {
        const float4* X4 = (const float4*)X;
#pragma unroll
        for (int g = 0; g < 4; g++) {
            float4 f0 = X4[t * 12 + g * 3 + 0];
            float4 f1 = X4[t * 12 + g * 3 + 1];
            float4 f2 = X4[t * 12 + g * 3 + 2];
            px[g*4+0] = f0.x; py[g*4+0] = f0.y; pz[g*4+0] = f0.z;
            px[g*4+1] = f0.w; py[g*4+1] = f1.x; pz[g*4+1] = f1.y;
            px[g*4+2] = f1.z; py[g*4+2] = f1.w; pz[g*4+2] = f2.x;
            px[g*4+3] = f2.y; py[g*4+3] = f2.z; pz[g*4+3] = f2.w;
        }
#pragma unroll
        for (int j = 0; j < 16; j++) {
            int p = t * 16 + j;
            sx[p] = px[j]; sy[p] = py[j]; sz[p] = pz[j];
            dist[j] = 1e10f;
        }
    }
    __syncthreads();

    float cx = sx[0], cy = sy[0], cz = sz[0];   // first sampled index is 0
    if (t == 0) {
        size_t o = (size_t)b * NSAMP * 3;
        new_xyz[o + 0] = cx; new_xyz[o + 1] = cy; new_xyz[o + 2] = cz;
    }

    int par = 0;
    for (int s = 1; s < NSAMP; s++) {
        // ---- update owned dists (exact numpy rounding: muls+adds, no fma) --
#pragma unroll
        for (int j = 0; j < 16; j++) {
            float dx = __fsub_rn(px[j], cx);
            float dy = __fsub_rn(py[j], cy);
            float dz = __fsub_rn(pz[j], cz);
            float d = __fadd_rn(__fadd_rn(__fmul_rn(dx, dx), __fmul_rn(dy, dy)),
                                __fmul_rn(dz, dz));
            dist[j] = fminf(dist[j], d);
        }
        // ---- per-thread argmax: log-depth max tree, then lowest-j match ----
        float mx[8];
#pragma unroll
        for (int j = 0; j < 8; j++) mx[j] = fmaxf(dist[2*j], dist[2*j+1]);
#pragma unroll
        for (int j = 0; j < 4; j++) mx[j] = fmaxf(mx[2*j], mx[2*j+1]);
        mx[0] = fmaxf(mx[0], mx[1]);
        float bv = fmaxf(mx[0], fmaxf(mx[2], mx[3]));
        int bj = 15;
#pragma unroll
        for (int j = 14; j >= 0; --j) bj = (dist[j] == bv) ? j : bj;

        // ---- wave reduce: f32 butterfly max, then recover winning lane -----
        float wmax = bv;
#pragma unroll
        for (int off = 32; off > 0; off >>= 1)
            wmax = fmaxf(wmax, __shfl_xor(wmax, off));
        unsigned long long em = __ballot(bv == wmax);
        int wl = __ffsll(em) - 1;              // lowest lane = lowest index
        int lidx = t * 16 + bj;
        int widx = __shfl(lidx, wl);
        if (lane == 0)
            wred[par][wv] = ((unsigned long long)__float_as_uint(wmax) << 32)
                          | (unsigned int)(~widx);
        __syncthreads();                       // the ONLY barrier per iter

        // ---- redundant cross-wave reduce (8 winners, LDS broadcast) --------
        unsigned long long r0 = wred[par][0], r1 = wred[par][1];
        unsigned long long r2 = wred[par][2], r3 = wred[par][3];
        unsigned long long r4 = wred[par][4], r5 = wred[par][5];
        unsigned long long r6 = wred[par][6], r7 = wred[par][7];
        if (r1 > r0) r0 = r1;
        if (r3 > r2) r2 = r3;
        if (r5 > r4) r4 = r5;
        if (r7 > r6) r6 = r7;
        if (r2 > r0) r0 = r2;
        if (r6 > r4) r4 = r6;
        if (r4 > r0) r0 = r4;
        int idx = (int)(~(unsigned int)(r0 & 0xFFFFFFFFull));

        cx = sx[idx]; cy = sy[idx]; cz = sz[idx];   // same-addr broadcast
        if (t == 0) {
            size_t o = ((size_t)b * NSAMP + s) * 3;
            new_xyz[o + 0] = cx; new_xyz[o + 1] = cy; new_xyz[o + 2] = cz;
        }
        par ^= 1;
    }
}

// ============================================================================
// K2: ball query. One wave per query; scan points in rounds of 64 in index
// order, collect first 16 within radius^2=0.04, pad with first. Early exit.
// ============================================================================
__global__ __launch_bounds__(256) void ballq_kernel(const float* __restrict__ xyz,
                                                    const float* __restrict__ new_xyz,
                                                    int* __restrict__ nidx) {
    const int wv = threadIdx.x >> 6, lane = threadIdx.x & 63;
    const int q = blockIdx.x * 4 + wv;          // 0..8191
    const int b = q >> 11;
    const float* X = xyz + (size_t)b * NPTS * 3;
    const float* Q = new_xyz + (size_t)q * 3;
    const float qx = Q[0], qy = Q[1], qz = Q[2];
    const float an = n3(qx, qy, qz);

    __shared__ int nb[4][NK];
    int cnt = 0;
    for (int base = 0; base < NPTS && cnt < NK; base += 64) {
        int p = base + lane;
        float x = X[p * 3 + 0], y = X[p * 3 + 1], z = X[p * 3 + 2];
        float bn = n3(x, y, z);
        float dt = dot3(qx, qy, qz, x, y, z);
        float sq = sqd_expand(an, bn, dt);
        bool in = (sq <= 0.04f);                // == (NOT sq > r^2)
        unsigned long long m = __ballot(in);
        if (in) {
            int pos = cnt + (int)__popcll(m & ((1ull << lane) - 1ull));
            if (pos < NK) nb[wv][pos] = p;
        }
        cnt += (int)__popcll(m);
    }
    __syncthreads();
    if (lane < NK) {
        int c = cnt < NK ? cnt : NK;
        int v = (lane < c) ? nb[wv][lane] : nb[wv][0];  // pad with first
        nidx[(size_t)q * NK + lane] = v;
    }
}

// ============================================================================
// K3: grouping + W1 (128x67) + relu + max over k -> subxT (B,2048,128)
// One wave per sample; lane c gathers feature channel c; per-k matvec with
// W1^T in LDS, grouped values broadcast via shfl.
// ============================================================================
__global__ __launch_bounds__(256) void group_mlp_kernel(const float* __restrict__ xyz,
                                                        const float* __restrict__ featT,
                                                        const float* __restrict__ new_xyz,
                                                        const int* __restrict__ nidx,
                                                        const float* __restrict__ W1,
                                                        float* __restrict__ subxT) {
    __shared__ float w1t[CG * CO1];   // [d][o], 33.5 KiB
    for (int i = threadIdx.x; i < CG * CO1; i += 256) {
        int d = i >> 7, o = i & 127;
        w1t[i] = W1[(size_t)o * CG + d];
    }
    __syncthreads();
    const int lane = threadIdx.x & 63, wv = threadIdx.x >> 6;

    for (int q = blockIdx.x * 4 + wv; q < BATCH * NSAMP; q += gridDim.x * 4) {
        const int b = q >> 11;
        const float* Q = new_xyz + (size_t)q * 3;
        const float qx = Q[0], qy = Q[1], qz = Q[2];
        const int* NB = nidx + (size_t)q * NK;
        float m0 = 0.0f, m1 = 0.0f;  // max(relu(h)) == max(0, max h)
#pragma unroll 1
        for (int k = 0; k < NK; k++) {
            const int n = NB[k];
            const float* P = xyz + ((size_t)b * NPTS + n) * 3;
            float rx = P[0] - qx, ry = P[1] - qy, rz = P[2] - qz;
            float fv = featT[((size_t)b * NPTS + n) * CFEAT + lane];
            float a0 = fmaf(w1t[0 * CO1 + lane], rx,
                       fmaf(w1t[1 * CO1 + lane], ry, w1t[2 * CO1 + lane] * rz));
            float a1 = fmaf(w1t[0 * CO1 + 64 + lane], rx,
                       fmaf(w1t[1 * CO1 + 64 + lane], ry, w1t[2 * CO1 + 64 + lane] * rz));
#pragma unroll
            for (int d = 3; d < CG; d++) {
                float g = __shfl(fv, d - 3);
                a0 = fmaf(w1t[d * CO1 + lane], g, a0);
                a1 = fmaf(w1t[d * CO1 + 64 + lane], g, a1);
            }
            m0 = fmaxf(m0, a0);
            m1 = fmaxf(m1, a1);
        }
        subxT[(size_t)q * CO1 + lane] = m0;
        subxT[(size_t)q * CO1 + 64 + lane] = m1;
    }
}

// ============================================================================
// K4: 3-NN interpolation + concat + W2 (128x192) + relu -> out (B,128,8192)
// One wave per output point. Top-3 via per-lane sorted insert + butterfly merge
// with (d, idx) lexicographic compare (== lax.top_k stability).
// ============================================================================
DEV void ins3(float dd, int jj,
              float& d0, int& i0, float& d1, int& i1, float& d2, int& i2) {
    bool c2 = (dd < d2) || (dd == d2 && jj < i2);
    if (c2) { d2 = dd; i2 = jj; }
    bool c1 = (d2 < d1) || (d2 == d1 && i2 < i1);
    if (c1) { float tv = d1; int ti = i1; d1 = d2; i1 = i2; d2 = tv; i2 = ti; }
    bool c0 = (d1 < d0) || (d1 == d0 && i1 < i0);
    if (c0) { float tv = d0; int ti = i0; d0 = d1; i0 = i1; d1 = tv; i1 = ti; }
}

__global__ __launch_bounds__(256) void interp_w2_kernel(const float* __restrict__ xyz,
                                                        const float* __restrict__ new_xyz,
                                                        const float* __restrict__ featT,
                                                        const float* __restrict__ subxT,
                                                        const float* __restrict__ W2,
                                                        float* __restrict__ out) {
    __shared__ float w2t[CCAT * CO2];  // [d][o], 96 KiB
    __shared__ float catb[4][CCAT];
    for (int i = threadIdx.x; i < CCAT * CO2; i += 256) {
        int d = i >> 7, o = i & 127;
        w2t[i] = W2[(size_t)o * CCAT + d];
    }
    __syncthreads();
    const int lane = threadIdx.x & 63, wv = threadIdx.x >> 6;

    for (int q = blockIdx.x * 4 + wv; q < BATCH * NPTS; q += gridDim.x * 4) {
        const int b = q >> 13, n = q & (NPTS - 1);
        const float* P = xyz + (size_t)q * 3;
        const float qx = P[0], qy = P[1], qz = P[2];
        const float an = n3(qx, qy, qz);

        float d0 = 1e30f, d1 = 1e30f, d2 = 1e30f;
        int i0 = 0x7fffffff, i1 = 0x7fffffff, i2 = 0x7fffffff;
        for (int j = lane; j < NSAMP; j += 64) {
            const float* C = new_xyz + ((size_t)b * NSAMP + j) * 3;
            float x = C[0], y = C[1], z = C[2];
            float bn = n3(x, y, z);
            float dt = dot3(qx, qy, qz, x, y, z);
            float dd = sqd_expand(an, bn, dt);
            ins3(dd, j, d0, i0, d1, i1, d2, i2);
        }
#pragma unroll
        for (int off = 32; off > 0; off >>= 1) {
            float e0 = __shfl_xor(d0, off); int f0 = __shfl_xor(i0, off);
            float e1 = __shfl_xor(d1, off); int f1 = __shfl_xor(i1, off);
            float e2 = __shfl_xor(d2, off); int f2 = __shfl_xor(i2, off);
            ins3(e0, f0, d0, i0, d1, i1, d2, i2);
            ins3(e1, f1, d0, i0, d1, i1, d2, i2);
            ins3(e2, f2, d0, i0, d1, i1, d2, i2);
        }
        float w0 = 1.0f / (d0 + 1e-8f);
        float w1 = 1.0f / (d1 + 1e-8f);
        float w2 = 1.0f / (d2 + 1e-8f);
        float sw = (w0 + w1) + w2;
        w0 /= sw; w1 /= sw; w2 /= sw;

        // lerp channels c=lane and c=lane+64 (coalesced row gathers)
        const float* S = subxT + (size_t)b * NSAMP * CO1;
        float L0 = S[(size_t)i0 * CO1 + lane] * w0
                 + S[(size_t)i1 * CO1 + lane] * w1
                 + S[(size_t)i2 * CO1 + lane] * w2;
        float L1 = S[(size_t)i0 * CO1 + 64 + lane] * w0
                 + S[(size_t)i1 * CO1 + 64 + lane] * w1
                 + S[(size_t)i2 * CO1 + 64 + lane] * w2;

        float fv = featT[((size_t)b * NPTS + n) * CFEAT + lane];
        catb[wv][lane] = fv;          // cat[0:64]   = features
        catb[wv][64 + lane] = L0;     // cat[64:128] = lerp lo
        catb[wv][128 + lane] = L1;    // cat[128:192]= lerp hi
        __builtin_amdgcn_s_waitcnt(0);  // drain ds_writes (in-order DS pipe, same wave)

        float a0 = 0.0f, a1 = 0.0f;
#pragma unroll 8
        for (int d = 0; d < CCAT; d++) {
            float cv = catb[wv][d];
            a0 = fmaf(w2t[d * CO2 + lane], cv, a0);
            a1 = fmaf(w2t[d * CO2 + 64 + lane], cv, a1);
        }
        out[((size_t)b * CO2 + lane) * NPTS + n] = fmaxf(a0, 0.0f);
        out[((size_t)b * CO2 + 64 + lane) * NPTS + n] = fmaxf(a1, 0.0f);
    }
}

// ============================================================================
extern "C" void kernel_launch(void* const* d_in, const int* in_sizes, int n_in,
                              void* d_out, int out_size, void* d_ws, size_t ws_size,
                              hipStream_t stream) {
    const float* xyz      = (const float*)d_in[0];  // (4,8192,3)
    const float* features = (const float*)d_in[1];  // (4,64,8192)
    const float* W1       = (const float*)d_in[2];  // (128,67)
    const float* W2       = (const float*)d_in[3];  // (128,192)
    float* out = (float*)d_out;                     // (4,128,8192)

    // workspace layout (floats/ints), total ~12.6 MB
    float* featT   = (float*)d_ws;                          // 4*8192*64
    float* new_xyz = featT + (size_t)BATCH * NPTS * CFEAT;  // 4*2048*3
    int*   nidx    = (int*)(new_xyz + (size_t)BATCH * NSAMP * 3); // 4*2048*16
    float* subxT   = (float*)(nidx + (size_t)BATCH * NSAMP * NK); // 4*2048*128

    transpose_kernel<<<dim3(NPTS / 64, BATCH), 256, 0, stream>>>(features, featT);
    fps_kernel<<<BATCH, 512, 0, stream>>>(xyz, new_xyz);
    ballq_kernel<<<(BATCH * NSAMP) / 4, 256, 0, stream>>>(xyz, new_xyz, nidx);
    group_mlp_kernel<<<512, 256, 0, stream>>>(xyz, featT, new_xyz, nidx, W1, subxT);
    interp_w2_kernel<<<256, 256, 0, stream>>>(xyz, new_xyz, featT, subxT, W2, out);
}